// Round 8
// baseline (1163.001 us; speedup 1.0000x reference)
//
#include <hip/hip_runtime.h>
#include <cstdint>
#include <cstddef>

#define N 8192
#define DIN 128
#define DTH 256
#define DOUT 128
#define ROWCAP 256

typedef float vfloat4 __attribute__((ext_vector_type(4)));

// ---------------- threefry2x32 with key (0, 42) --------------------------
__device__ __forceinline__ void threefry_0_42(uint32_t x0, uint32_t x1,
                                              uint32_t& o0, uint32_t& o1) {
  const uint32_t ks0 = 0u;
  const uint32_t ks1 = 42u;
  const uint32_t ks2 = 0x1BD11BDAu ^ 0u ^ 42u;
  x0 += ks0; x1 += ks1;
#define TF_R(r) { x0 += x1; x1 = (x1 << (r)) | (x1 >> (32 - (r))); x1 ^= x0; }
  TF_R(13) TF_R(15) TF_R(26) TF_R(6)
  x0 += ks1; x1 += ks2 + 1u;
  TF_R(17) TF_R(29) TF_R(16) TF_R(24)
  x0 += ks2; x1 += ks0 + 2u;
  TF_R(13) TF_R(15) TF_R(26) TF_R(6)
  x0 += ks0; x1 += ks1 + 3u;
  TF_R(17) TF_R(29) TF_R(16) TF_R(24)
  x0 += ks1; x1 += ks2 + 4u;
  TF_R(13) TF_R(15) TF_R(26) TF_R(6)
  x0 += ks2; x1 += ks0 + 5u;
#undef TF_R
  o0 = x0; o1 = x1;
}

__device__ __forceinline__ bool dropedge_keep(uint32_t t) {
  uint32_t y0, y1;
  threefry_0_42(0u, t, y0, y1);
  uint32_t bits = y0 ^ y1;
  float u = __uint_as_float((bits >> 9) | 0x3f800000u) - 1.0f;
  return u < 0.8f;
}

__device__ __forceinline__ unsigned short f2bf(float v) {
  uint32_t u = __float_as_uint(v);
  u += 0x7fffu + ((u >> 16) & 1u);     // round-to-nearest-even
  return (unsigned short)(u >> 16);
}

// ---------------- K1: BN partial sums + W pack ---------------------------
// blocks [0,64): BN partial sums; [64,256): Wc pack; [256,258): bc.
__global__ __launch_bounds__(256) void k_pre(
    const float* __restrict__ H,
    const float* __restrict__ Wt, const float* __restrict__ bt,
    const float* __restrict__ Wo, const float* __restrict__ bo,
    float* __restrict__ part_s, float* __restrict__ part_s2,
    float* __restrict__ Wc, float* __restrict__ bc) {
  int b = blockIdx.x;
  int tid = threadIdx.x;
  if (b < 64) {
    __shared__ float ls[8][DIN];
    __shared__ float ls2[8][DIN];
    int rg = tid >> 5;
    int c4 = tid & 31;
    int rbase = b * 128;
    float s[4] = {0,0,0,0}, s2[4] = {0,0,0,0};
    for (int k = 0; k < 16; ++k) {
      int r = rbase + rg + k * 8;
      float4 h = ((const float4*)(H + (size_t)r * DIN))[c4];
      s[0] += h.x; s2[0] += h.x * h.x;
      s[1] += h.y; s2[1] += h.y * h.y;
      s[2] += h.z; s2[2] += h.z * h.z;
      s[3] += h.w; s2[3] += h.w * h.w;
    }
#pragma unroll
    for (int q = 0; q < 4; ++q) { ls[rg][c4*4+q] = s[q]; ls2[rg][c4*4+q] = s2[q]; }
    __syncthreads();
    if (tid < DIN) {
      float a = 0.f, bb = 0.f;
#pragma unroll
      for (int g = 0; g < 8; ++g) { a += ls[g][tid]; bb += ls2[g][tid]; }
      part_s[b * DIN + tid] = a;
      part_s2[b * DIN + tid] = bb;
    }
  } else if (b < 256) {
    int idx = (b - 64) * 256 + tid;        // [0, 49152)
    int k = idx / 384, c = idx % 384;
    Wc[idx] = (c < 256) ? Wt[(size_t)c * DIN + k] : Wo[(size_t)(c - 256) * DIN + k];
  } else {
    int c = (b - 256) * 256 + tid;
    if (c < 384) bc[c] = (c < 256) ? bt[c] : bo[c - 256];
  }
}

// ---------------- K2: pure GEMM: Hxh(bf16) / HW / sq ---------------------
__global__ __launch_bounds__(256) void k_rows(
    const float* __restrict__ H,
    const float* __restrict__ part_s, const float* __restrict__ part_s2,
    const float* __restrict__ gamma, const float* __restrict__ beta,
    const float* __restrict__ Wc, const float* __restrict__ bc,
    unsigned short* __restrict__ Hxh, float* __restrict__ HW,
    float* __restrict__ sq) {
  int tid = threadIdx.x;
  int b = blockIdx.x;
  __shared__ __align__(16) float ssc[DIN];
  __shared__ __align__(16) float ssh[DIN];
  __shared__ float hn[16][DIN];   // 8 KB; reads below are wave-broadcast
  // inline BN finalize (identical bit-exact result in every block)
  if (tid < DIN) {
    float s = 0.f, s2 = 0.f;
    for (int g = 0; g < 64; ++g) { s += part_s[g*DIN+tid]; s2 += part_s2[g*DIN+tid]; }
    float mean = s * (1.0f / N);
    float var  = s2 * (1.0f / N) - mean * mean;
    float sc = rsqrtf(var + 1e-5f) * gamma[tid];
    ssc[tid] = sc;
    ssh[tid] = beta[tid] - mean * sc;
  }
  __syncthreads();
  int base = b * 16;
#pragma unroll
  for (int k = 0; k < 2; ++k) {
    int f = tid + k * 256;
    int r = f >> 5, c4 = f & 31;
    float4 h  = ((const float4*)(H + (size_t)(base + r) * DIN))[c4];
    float4 sc = ((const float4*)ssc)[c4];
    float4 sh = ((const float4*)ssh)[c4];
    h.x = h.x * sc.x + sh.x; h.y = h.y * sc.y + sh.y;
    h.z = h.z * sc.z + sh.z; h.w = h.w * sc.w + sh.w;
    ((float4*)hn[r])[c4] = h;
  }
  __syncthreads();
  int w = tid >> 6, lane = tid & 63;
  int r0 = w * 4;
  float acc[4][6];
#pragma unroll
  for (int r = 0; r < 4; ++r)
#pragma unroll
    for (int q = 0; q < 6; ++q) acc[r][q] = 0.f;

  for (int k4 = 0; k4 < 32; ++k4) {
    float4 h[4];
#pragma unroll
    for (int r = 0; r < 4; ++r) h[r] = ((const float4*)hn[r0 + r])[k4];
#pragma unroll
    for (int kk = 0; kk < 4; ++kk) {
      const float* wrow = Wc + (size_t)(k4 * 4 + kk) * 384 + lane;
      float wv[6];
#pragma unroll
      for (int q = 0; q < 6; ++q) wv[q] = wrow[64 * q];
#pragma unroll
      for (int r = 0; r < 4; ++r) {
        float hs = (kk == 0) ? h[r].x : (kk == 1) ? h[r].y
                 : (kk == 2) ? h[r].z : h[r].w;
#pragma unroll
        for (int q = 0; q < 6; ++q) acc[r][q] += hs * wv[q];
      }
    }
  }
#pragma unroll
  for (int r = 0; r < 4; ++r) {
    int row = base + r0 + r;
    float s = 0.f;
#pragma unroll
    for (int q = 0; q < 4; ++q) {
      float v = acc[r][q] + bc[lane + 64 * q];
      Hxh[(size_t)row * DTH + lane + 64 * q] = f2bf(v);
      s += v * v;
    }
#pragma unroll
    for (int off = 32; off > 0; off >>= 1) s += __shfl_xor(s, off, 64);
    if (lane == 0) sq[row] = s;
#pragma unroll
    for (int q = 4; q < 6; ++q) {
      float v = acc[r][q] + bc[lane + 64 * q];
      HW[(size_t)row * DOUT + lane + 64 * (q - 4)] = v;
    }
  }
}

// ---------------- K3: one block per row: read A_adj row, compute edges ---
// in-register, write full A3 row. No zero pass, no scatter, no global
// atomics (row i owns deg[i]/nnz[i]; symmetric values recomputed per side
// with identical keep-bit via min/max flat index).
__global__ __launch_bounds__(256) void k_scan(
    const float* __restrict__ A_adj, const unsigned short* __restrict__ Hxh,
    const float* __restrict__ sq, float* __restrict__ A3,
    float* __restrict__ deg, int* __restrict__ nnz_cnt,
    int* __restrict__ nnz_idx, float* __restrict__ nnz_val) {
  int i = blockIdx.x;
  int tid = threadIdx.x;    // 256
  __shared__ float4 hx4[64];            // hx_i as 64 float4
  __shared__ float s_deg[4];
  __shared__ int s_cnt;
  __shared__ unsigned short s_j[ROWCAP];
  __shared__ float s_v[ROWCAP];
  if (tid == 0) s_cnt = 0;
  ((float*)hx4)[tid] = __uint_as_float(((uint32_t)Hxh[(size_t)i * DTH + tid]) << 16);
  __syncthreads();

  // prefetch entire A_adj row: 8 float4 per lane, coalesced
  const vfloat4* arow = (const vfloat4*)(A_adj + (size_t)i * N);
  vfloat4 a[8];
#pragma unroll
  for (int it = 0; it < 8; ++it)
    a[it] = __builtin_nontemporal_load(arow + tid + it * 256);

  float sqi = sq[i];
  float dsum = 0.f;
  vfloat4* orow = (vfloat4*)(A3 + (size_t)i * N);
#pragma unroll
  for (int it = 0; it < 8; ++it) {
    float av[4] = {a[it].x, a[it].y, a[it].z, a[it].w};
    float ov[4] = {0.f, 0.f, 0.f, 0.f};
    int jb = (tid + it * 256) * 4;
#pragma unroll
    for (int q = 0; q < 4; ++q) {
      if (av[q] != 0.f) {
        int j = jb + q;
        uint32_t r = (uint32_t)min(i, j), c = (uint32_t)max(i, j);
        bool keep = dropedge_keep(r * (uint32_t)N + c);
        float dist;
        if (j == i) {
          dist = 1e-6f;                  // exact diagonal: sqrt(clip(0,1e-12))
        } else {
          const uint4* hj = (const uint4*)(Hxh + (size_t)j * DTH);
          float dot = 0.f;
#pragma unroll 8
          for (int cc = 0; cc < 32; ++cc) {
            uint4 u = hj[cc];
            float4 f0 = hx4[2 * cc], f1 = hx4[2 * cc + 1];
            dot += __uint_as_float(u.x << 16) * f0.x
                 + __uint_as_float(u.x & 0xffff0000u) * f0.y
                 + __uint_as_float(u.y << 16) * f0.z
                 + __uint_as_float(u.y & 0xffff0000u) * f0.w
                 + __uint_as_float(u.z << 16) * f1.x
                 + __uint_as_float(u.z & 0xffff0000u) * f1.y
                 + __uint_as_float(u.w << 16) * f1.z
                 + __uint_as_float(u.w & 0xffff0000u) * f1.w;
          }
          dist = sqrtf(fmaxf(sqi + sq[j] - 2.0f * dot, 1e-12f));
        }
        float aval = expf(-0.2f * dist);
        float sg = fmaxf(1.0f / (1.0f + expf(-aval)), 0.1f);
        float bb = keep ? sg : 0.0f;
        float a2 = bb + ((j == i) ? 1.0f : 0.0f);
        float a3v = (a2 > 0.6f) ? a2 : 0.0f;
        if (a3v != 0.f) {
          ov[q] = a3v;
          dsum += a3v;
          int p = atomicAdd(&s_cnt, 1);
          if (p < ROWCAP) { s_j[p] = (unsigned short)j; s_v[p] = a3v; }
        }
      }
    }
    vfloat4 o = {ov[0], ov[1], ov[2], ov[3]};
    __builtin_nontemporal_store(o, orow + tid + it * 256);
  }
  // block-level deg reduction (no global atomics)
#pragma unroll
  for (int off = 32; off > 0; off >>= 1) dsum += __shfl_xor(dsum, off, 64);
  if ((tid & 63) == 0) s_deg[tid >> 6] = dsum;
  __syncthreads();
  if (tid == 0) {
    deg[i] = s_deg[0] + s_deg[1] + s_deg[2] + s_deg[3];
    nnz_cnt[i] = min(s_cnt, ROWCAP);
  }
  int M = min(s_cnt, ROWCAP);
  for (int t = tid; t < M; t += 256) {
    nnz_idx[(size_t)i * ROWCAP + t] = s_j[t];
    nnz_val[(size_t)i * ROWCAP + t] = s_v[t];
  }
}

// ---------------- K4: out = lrelu(D^-1/2 A3 D^-1/2 @ HW) -----------------
__global__ __launch_bounds__(128) void k_post(
    const float* __restrict__ HW, const float* __restrict__ deg,
    const int* __restrict__ nnz_cnt, const int* __restrict__ nnz_idx,
    const float* __restrict__ nnz_val, float* __restrict__ out) {
  int i = blockIdx.x;
  int c = threadIdx.x;      // 128
  int cnt = min(nnz_cnt[i], ROWCAP);
  float acc = 0.f;
  for (int e = 0; e < cnt; ++e) {
    int j = nnz_idx[(size_t)i * ROWCAP + e];
    float v = nnz_val[(size_t)i * ROWCAP + e];
    acc += v * rsqrtf(deg[j]) * HW[(size_t)j * DOUT + c];
  }
  float o = rsqrtf(deg[i]) * acc;
  out[(size_t)i * DOUT + c] = (o >= 0.f) ? o : 0.01f * o;
}

// ---------------- launch --------------------------------------------------
extern "C" void kernel_launch(void* const* d_in, const int* in_sizes, int n_in,
                              void* d_out, int out_size, void* d_ws, size_t ws_size,
                              hipStream_t stream) {
  const float* H     = (const float*)d_in[0];
  const float* A_adj = (const float*)d_in[1];
  const float* gamma = (const float*)d_in[2];
  const float* beta  = (const float*)d_in[3];
  const float* Wt    = (const float*)d_in[4];
  const float* bt    = (const float*)d_in[5];
  const float* Wo    = (const float*)d_in[6];
  const float* bo    = (const float*)d_in[7];

  float* out = (float*)d_out;                    // [N, DOUT]
  float* A3  = out + (size_t)N * DOUT;           // [N, N]

  float* ws    = (float*)d_ws;
  unsigned short* Hxh = (unsigned short*)ws;      // N*256 bf16 (= N*128 floats)
  float* sq    = ws + (size_t)N * 128;            // N
  float* HW    = sq + N;                          // N*128
  float* deg   = HW + (size_t)N * DOUT;           // N
  int*   nnz_cnt = (int*)(deg + N);               // N
  int*   nnz_idx = nnz_cnt + N;                   // N*ROWCAP
  float* nnz_val = (float*)(nnz_idx + (size_t)N * ROWCAP); // N*ROWCAP
  float* part_s  = nnz_val + (size_t)N * ROWCAP;  // 64*128
  float* part_s2 = part_s + 64 * DIN;             // 64*128
  float* Wc      = part_s2 + 64 * DIN;            // 128*384
  float* bc      = Wc + 128 * 384;                // 384

  k_pre<<<258, 256, 0, stream>>>(H, Wt, bt, Wo, bo, part_s, part_s2, Wc, bc);
  k_rows<<<N / 16, 256, 0, stream>>>(H, part_s, part_s2, gamma, beta, Wc, bc,
                                     Hxh, HW, sq);
  k_scan<<<N, 256, 0, stream>>>(A_adj, Hxh, sq, A3, deg, nnz_cnt, nnz_idx, nnz_val);
  k_post<<<N, DOUT, 0, stream>>>(HW, deg, nnz_cnt, nnz_idx, nnz_val, out);
}

// Round 9
// 506.033 us; speedup vs baseline: 2.2983x; 2.2983x over previous
//
#include <hip/hip_runtime.h>
#include <cstdint>
#include <cstddef>

#define N 8192
#define DIN 128
#define DTH 256
#define DOUT 128
#define ROWCAP 256

typedef float vfloat4 __attribute__((ext_vector_type(4)));

// ---------------- threefry2x32 with key (0, 42) --------------------------
__device__ __forceinline__ void threefry_0_42(uint32_t x0, uint32_t x1,
                                              uint32_t& o0, uint32_t& o1) {
  const uint32_t ks0 = 0u;
  const uint32_t ks1 = 42u;
  const uint32_t ks2 = 0x1BD11BDAu ^ 0u ^ 42u;
  x0 += ks0; x1 += ks1;
#define TF_R(r) { x0 += x1; x1 = (x1 << (r)) | (x1 >> (32 - (r))); x1 ^= x0; }
  TF_R(13) TF_R(15) TF_R(26) TF_R(6)
  x0 += ks1; x1 += ks2 + 1u;
  TF_R(17) TF_R(29) TF_R(16) TF_R(24)
  x0 += ks2; x1 += ks0 + 2u;
  TF_R(13) TF_R(15) TF_R(26) TF_R(6)
  x0 += ks0; x1 += ks1 + 3u;
  TF_R(17) TF_R(29) TF_R(16) TF_R(24)
  x0 += ks1; x1 += ks2 + 4u;
  TF_R(13) TF_R(15) TF_R(26) TF_R(6)
  x0 += ks2; x1 += ks0 + 5u;
#undef TF_R
  o0 = x0; o1 = x1;
}

__device__ __forceinline__ bool dropedge_keep(uint32_t t) {
  uint32_t y0, y1;
  threefry_0_42(0u, t, y0, y1);
  uint32_t bits = y0 ^ y1;
  float u = __uint_as_float((bits >> 9) | 0x3f800000u) - 1.0f;
  return u < 0.8f;
}

__device__ __forceinline__ unsigned short f2bf(float v) {
  uint32_t u = __float_as_uint(v);
  u += 0x7fffu + ((u >> 16) & 1u);     // round-to-nearest-even
  return (unsigned short)(u >> 16);
}

// ---------------- K1: BN partial sums + W pack ---------------------------
// blocks [0,64): BN partial sums; [64,256): Wc pack; [256,258): bc.
__global__ __launch_bounds__(256) void k_pre(
    const float* __restrict__ H,
    const float* __restrict__ Wt, const float* __restrict__ bt,
    const float* __restrict__ Wo, const float* __restrict__ bo,
    float* __restrict__ part_s, float* __restrict__ part_s2,
    float* __restrict__ Wc, float* __restrict__ bc) {
  int b = blockIdx.x;
  int tid = threadIdx.x;
  if (b < 64) {
    __shared__ float ls[8][DIN];
    __shared__ float ls2[8][DIN];
    int rg = tid >> 5;
    int c4 = tid & 31;
    int rbase = b * 128;
    float s[4] = {0,0,0,0}, s2[4] = {0,0,0,0};
    for (int k = 0; k < 16; ++k) {
      int r = rbase + rg + k * 8;
      float4 h = ((const float4*)(H + (size_t)r * DIN))[c4];
      s[0] += h.x; s2[0] += h.x * h.x;
      s[1] += h.y; s2[1] += h.y * h.y;
      s[2] += h.z; s2[2] += h.z * h.z;
      s[3] += h.w; s2[3] += h.w * h.w;
    }
#pragma unroll
    for (int q = 0; q < 4; ++q) { ls[rg][c4*4+q] = s[q]; ls2[rg][c4*4+q] = s2[q]; }
    __syncthreads();
    if (tid < DIN) {
      float a = 0.f, bb = 0.f;
#pragma unroll
      for (int g = 0; g < 8; ++g) { a += ls[g][tid]; bb += ls2[g][tid]; }
      part_s[b * DIN + tid] = a;
      part_s2[b * DIN + tid] = bb;
    }
  } else if (b < 256) {
    int idx = (b - 64) * 256 + tid;        // [0, 49152)
    int k = idx / 384, c = idx % 384;
    Wc[idx] = (c < 256) ? Wt[(size_t)c * DIN + k] : Wo[(size_t)(c - 256) * DIN + k];
  } else {
    int c = (b - 256) * 256 + tid;
    if (c < 384) bc[c] = (c < 256) ? bt[c] : bo[c - 256];
  }
}

// ---------------- K2: pure GEMM: Hxh(bf16) / HW / sq ---------------------
__global__ __launch_bounds__(256) void k_rows(
    const float* __restrict__ H,
    const float* __restrict__ part_s, const float* __restrict__ part_s2,
    const float* __restrict__ gamma, const float* __restrict__ beta,
    const float* __restrict__ Wc, const float* __restrict__ bc,
    unsigned short* __restrict__ Hxh, float* __restrict__ HW,
    float* __restrict__ sq) {
  int tid = threadIdx.x;
  int b = blockIdx.x;
  __shared__ __align__(16) float ssc[DIN];
  __shared__ __align__(16) float ssh[DIN];
  __shared__ float hn[16][DIN];   // 8 KB; reads below are wave-broadcast
  // inline BN finalize (identical bit-exact result in every block)
  if (tid < DIN) {
    float s = 0.f, s2 = 0.f;
    for (int g = 0; g < 64; ++g) { s += part_s[g*DIN+tid]; s2 += part_s2[g*DIN+tid]; }
    float mean = s * (1.0f / N);
    float var  = s2 * (1.0f / N) - mean * mean;
    float sc = rsqrtf(var + 1e-5f) * gamma[tid];
    ssc[tid] = sc;
    ssh[tid] = beta[tid] - mean * sc;
  }
  __syncthreads();
  int base = b * 16;
#pragma unroll
  for (int k = 0; k < 2; ++k) {
    int f = tid + k * 256;
    int r = f >> 5, c4 = f & 31;
    float4 h  = ((const float4*)(H + (size_t)(base + r) * DIN))[c4];
    float4 sc = ((const float4*)ssc)[c4];
    float4 sh = ((const float4*)ssh)[c4];
    h.x = h.x * sc.x + sh.x; h.y = h.y * sc.y + sh.y;
    h.z = h.z * sc.z + sh.z; h.w = h.w * sc.w + sh.w;
    ((float4*)hn[r])[c4] = h;
  }
  __syncthreads();
  int w = tid >> 6, lane = tid & 63;
  int r0 = w * 4;
  float acc[4][6];
#pragma unroll
  for (int r = 0; r < 4; ++r)
#pragma unroll
    for (int q = 0; q < 6; ++q) acc[r][q] = 0.f;

  for (int k4 = 0; k4 < 32; ++k4) {
    float4 h[4];
#pragma unroll
    for (int r = 0; r < 4; ++r) h[r] = ((const float4*)hn[r0 + r])[k4];
#pragma unroll
    for (int kk = 0; kk < 4; ++kk) {
      const float* wrow = Wc + (size_t)(k4 * 4 + kk) * 384 + lane;
      float wv[6];
#pragma unroll
      for (int q = 0; q < 6; ++q) wv[q] = wrow[64 * q];
#pragma unroll
      for (int r = 0; r < 4; ++r) {
        float hs = (kk == 0) ? h[r].x : (kk == 1) ? h[r].y
                 : (kk == 2) ? h[r].z : h[r].w;
#pragma unroll
        for (int q = 0; q < 6; ++q) acc[r][q] += hs * wv[q];
      }
    }
  }
#pragma unroll
  for (int r = 0; r < 4; ++r) {
    int row = base + r0 + r;
    float s = 0.f;
#pragma unroll
    for (int q = 0; q < 4; ++q) {
      float v = acc[r][q] + bc[lane + 64 * q];
      Hxh[(size_t)row * DTH + lane + 64 * q] = f2bf(v);
      s += v * v;
    }
#pragma unroll
    for (int off = 32; off > 0; off >>= 1) s += __shfl_xor(s, off, 64);
    if (lane == 0) sq[row] = s;
#pragma unroll
    for (int q = 4; q < 6; ++q) {
      float v = acc[r][q] + bc[lane + 64 * q];
      HW[(size_t)row * DOUT + lane + 64 * (q - 4)] = v;
    }
  }
}

// ---------------- K3: one block per row via LDS row buffer ---------------
// (A) prefetch A_adj row + zero 32KB LDS rowbuf + COMPACT edge columns;
// (B) dense edge loop (full lane efficiency) scatters survivors into LDS;
// (C) stream finished row to A3 (nontemporal). No zero pass, no global
// atomics, no RMW scatter.
__global__ __launch_bounds__(256) void k_scan(
    const float* __restrict__ A_adj, const unsigned short* __restrict__ Hxh,
    const float* __restrict__ sq, float* __restrict__ A3,
    float* __restrict__ deg, int* __restrict__ nnz_cnt,
    int* __restrict__ nnz_idx, float* __restrict__ nnz_val) {
  int i = blockIdx.x;
  int tid = threadIdx.x;    // 256
  __shared__ float rowbuf[N];           // 32 KB
  __shared__ float4 hx4[64];            // hx_i as 64 float4
  __shared__ unsigned short s_j[ROWCAP];
  __shared__ float s_deg[4];
  __shared__ int s_cnt, s_nz;
  if (tid == 0) { s_cnt = 0; s_nz = 0; }
  ((float*)hx4)[tid] = __uint_as_float(((uint32_t)Hxh[(size_t)i * DTH + tid]) << 16);

  // prefetch entire A_adj row: 8 float4 per lane, coalesced
  const vfloat4* arow = (const vfloat4*)(A_adj + (size_t)i * N);
  vfloat4 a[8];
#pragma unroll
  for (int it = 0; it < 8; ++it)
    a[it] = __builtin_nontemporal_load(arow + tid + it * 256);
  // zero LDS rowbuf while loads are in flight
  const vfloat4 z = {0.f, 0.f, 0.f, 0.f};
#pragma unroll
  for (int it = 0; it < 8; ++it)
    ((vfloat4*)rowbuf)[tid + it * 256] = z;
  __syncthreads();

  // compact nonzero columns into s_j
#pragma unroll
  for (int it = 0; it < 8; ++it) {
    float av[4] = {a[it].x, a[it].y, a[it].z, a[it].w};
    int jb = (tid + it * 256) * 4;
#pragma unroll
    for (int q = 0; q < 4; ++q) {
      if (av[q] != 0.f) {
        int p = atomicAdd(&s_cnt, 1);
        if (p < ROWCAP) s_j[p] = (unsigned short)(jb + q);
      }
    }
  }
  __syncthreads();

  int M = min(s_cnt, ROWCAP);
  float sqi = sq[i];
  float dsum = 0.f;
  for (int t = tid; t < M; t += 256) {
    int j = s_j[t];
    uint32_t r = (uint32_t)min(i, j), c = (uint32_t)max(i, j);
    bool keep = dropedge_keep(r * (uint32_t)N + c);
    float dist;
    if (j == i) {
      dist = 1e-6f;                      // exact diagonal: sqrt(clip(0,1e-12))
    } else {
      const uint4* hj = (const uint4*)(Hxh + (size_t)j * DTH);
      float dot = 0.f;
#pragma unroll 8
      for (int cc = 0; cc < 32; ++cc) {
        uint4 u = hj[cc];
        float4 f0 = hx4[2 * cc], f1 = hx4[2 * cc + 1];
        dot += __uint_as_float(u.x << 16) * f0.x
             + __uint_as_float(u.x & 0xffff0000u) * f0.y
             + __uint_as_float(u.y << 16) * f0.z
             + __uint_as_float(u.y & 0xffff0000u) * f0.w
             + __uint_as_float(u.z << 16) * f1.x
             + __uint_as_float(u.z & 0xffff0000u) * f1.y
             + __uint_as_float(u.w << 16) * f1.z
             + __uint_as_float(u.w & 0xffff0000u) * f1.w;
      }
      dist = sqrtf(fmaxf(sqi + sq[j] - 2.0f * dot, 1e-12f));
    }
    float aval = expf(-0.2f * dist);
    float sg = fmaxf(1.0f / (1.0f + expf(-aval)), 0.1f);
    float bb = keep ? sg : 0.0f;
    float a2 = bb + ((j == i) ? 1.0f : 0.0f);
    float a3v = (a2 > 0.6f) ? a2 : 0.0f;
    if (a3v != 0.f) {
      rowbuf[j] = a3v;
      dsum += a3v;
      int p = atomicAdd(&s_nz, 1);
      nnz_idx[(size_t)i * ROWCAP + p] = j;
      nnz_val[(size_t)i * ROWCAP + p] = a3v;
    }
  }
  // block-level deg reduction
#pragma unroll
  for (int off = 32; off > 0; off >>= 1) dsum += __shfl_xor(dsum, off, 64);
  if ((tid & 63) == 0) s_deg[tid >> 6] = dsum;
  __syncthreads();
  if (tid == 0) {
    deg[i] = s_deg[0] + s_deg[1] + s_deg[2] + s_deg[3];
    nnz_cnt[i] = min(s_nz, ROWCAP);
  }
  // stream finished row out
  vfloat4* orow = (vfloat4*)(A3 + (size_t)i * N);
#pragma unroll
  for (int it = 0; it < 8; ++it) {
    vfloat4 v = ((const vfloat4*)rowbuf)[tid + it * 256];
    __builtin_nontemporal_store(v, orow + tid + it * 256);
  }
}

// ---------------- K4: out = lrelu(D^-1/2 A3 D^-1/2 @ HW) -----------------
__global__ __launch_bounds__(128) void k_post(
    const float* __restrict__ HW, const float* __restrict__ deg,
    const int* __restrict__ nnz_cnt, const int* __restrict__ nnz_idx,
    const float* __restrict__ nnz_val, float* __restrict__ out) {
  int i = blockIdx.x;
  int c = threadIdx.x;      // 128
  int cnt = min(nnz_cnt[i], ROWCAP);
  float acc = 0.f;
  for (int e = 0; e < cnt; ++e) {
    int j = nnz_idx[(size_t)i * ROWCAP + e];
    float v = nnz_val[(size_t)i * ROWCAP + e];
    acc += v * rsqrtf(deg[j]) * HW[(size_t)j * DOUT + c];
  }
  float o = rsqrtf(deg[i]) * acc;
  out[(size_t)i * DOUT + c] = (o >= 0.f) ? o : 0.01f * o;
}

// ---------------- launch --------------------------------------------------
extern "C" void kernel_launch(void* const* d_in, const int* in_sizes, int n_in,
                              void* d_out, int out_size, void* d_ws, size_t ws_size,
                              hipStream_t stream) {
  const float* H     = (const float*)d_in[0];
  const float* A_adj = (const float*)d_in[1];
  const float* gamma = (const float*)d_in[2];
  const float* beta  = (const float*)d_in[3];
  const float* Wt    = (const float*)d_in[4];
  const float* bt    = (const float*)d_in[5];
  const float* Wo    = (const float*)d_in[6];
  const float* bo    = (const float*)d_in[7];

  float* out = (float*)d_out;                    // [N, DOUT]
  float* A3  = out + (size_t)N * DOUT;           // [N, N]

  float* ws    = (float*)d_ws;
  unsigned short* Hxh = (unsigned short*)ws;      // N*256 bf16 (= N*128 floats)
  float* sq    = ws + (size_t)N * 128;            // N
  float* HW    = sq + N;                          // N*128
  float* deg   = HW + (size_t)N * DOUT;           // N
  int*   nnz_cnt = (int*)(deg + N);               // N
  int*   nnz_idx = nnz_cnt + N;                   // N*ROWCAP
  float* nnz_val = (float*)(nnz_idx + (size_t)N * ROWCAP); // N*ROWCAP
  float* part_s  = nnz_val + (size_t)N * ROWCAP;  // 64*128
  float* part_s2 = part_s + 64 * DIN;             // 64*128
  float* Wc      = part_s2 + 64 * DIN;            // 128*384
  float* bc      = Wc + 128 * 384;                // 384

  k_pre<<<258, 256, 0, stream>>>(H, Wt, bt, Wo, bo, part_s, part_s2, Wc, bc);
  k_rows<<<N / 16, 256, 0, stream>>>(H, part_s, part_s2, gamma, beta, Wc, bc,
                                     Hxh, HW, sq);
  k_scan<<<N, 256, 0, stream>>>(A_adj, Hxh, sq, A3, deg, nnz_cnt, nnz_idx, nnz_val);
  k_post<<<N, DOUT, 0, stream>>>(HW, deg, nnz_cnt, nnz_idx, nnz_val, out);
}

// Round 10
// 462.590 us; speedup vs baseline: 2.5141x; 1.0939x over previous
//
#include <hip/hip_runtime.h>
#include <cstdint>
#include <cstddef>

#define N 8192
#define DIN 128
#define DTH 256
#define DOUT 128
#define ROWCAP 256
#define LISTCAP 256

typedef float vfloat4 __attribute__((ext_vector_type(4)));

// ---------------- threefry2x32 with key (0, 42) --------------------------
__device__ __forceinline__ void threefry_0_42(uint32_t x0, uint32_t x1,
                                              uint32_t& o0, uint32_t& o1) {
  const uint32_t ks0 = 0u;
  const uint32_t ks1 = 42u;
  const uint32_t ks2 = 0x1BD11BDAu ^ 0u ^ 42u;
  x0 += ks0; x1 += ks1;
#define TF_R(r) { x0 += x1; x1 = (x1 << (r)) | (x1 >> (32 - (r))); x1 ^= x0; }
  TF_R(13) TF_R(15) TF_R(26) TF_R(6)
  x0 += ks1; x1 += ks2 + 1u;
  TF_R(17) TF_R(29) TF_R(16) TF_R(24)
  x0 += ks2; x1 += ks0 + 2u;
  TF_R(13) TF_R(15) TF_R(26) TF_R(6)
  x0 += ks0; x1 += ks1 + 3u;
  TF_R(17) TF_R(29) TF_R(16) TF_R(24)
  x0 += ks1; x1 += ks2 + 4u;
  TF_R(13) TF_R(15) TF_R(26) TF_R(6)
  x0 += ks2; x1 += ks0 + 5u;
#undef TF_R
  o0 = x0; o1 = x1;
}

__device__ __forceinline__ bool dropedge_keep(uint32_t t) {
  uint32_t y0, y1;
  threefry_0_42(0u, t, y0, y1);
  uint32_t bits = y0 ^ y1;
  float u = __uint_as_float((bits >> 9) | 0x3f800000u) - 1.0f;
  return u < 0.8f;
}

__device__ __forceinline__ unsigned short f2bf(float v) {
  uint32_t u = __float_as_uint(v);
  u += 0x7fffu + ((u >> 16) & 1u);     // round-to-nearest-even
  return (unsigned short)(u >> 16);
}

// ---------------- K1: fused bn_part + W pack + counter zero --------------
// blocks [0,64): BN partial sums; [64,256): Wc pack; [256,258): bc;
// [258,274): zero deg + nnz_cnt (contiguous 64 KB).
__global__ __launch_bounds__(256) void k_pre(
    const float* __restrict__ H,
    const float* __restrict__ Wt, const float* __restrict__ bt,
    const float* __restrict__ Wo, const float* __restrict__ bo,
    float* __restrict__ part_s, float* __restrict__ part_s2,
    float* __restrict__ Wc, float* __restrict__ bc,
    float* __restrict__ deg /* deg + nnz_cnt contiguous */) {
  int b = blockIdx.x;
  int tid = threadIdx.x;
  if (b < 64) {
    __shared__ float ls[8][DIN];
    __shared__ float ls2[8][DIN];
    int rg = tid >> 5;
    int c4 = tid & 31;
    int rbase = b * 128;
    float s[4] = {0,0,0,0}, s2[4] = {0,0,0,0};
    for (int k = 0; k < 16; ++k) {
      int r = rbase + rg + k * 8;
      float4 h = ((const float4*)(H + (size_t)r * DIN))[c4];
      s[0] += h.x; s2[0] += h.x * h.x;
      s[1] += h.y; s2[1] += h.y * h.y;
      s[2] += h.z; s2[2] += h.z * h.z;
      s[3] += h.w; s2[3] += h.w * h.w;
    }
#pragma unroll
    for (int q = 0; q < 4; ++q) { ls[rg][c4*4+q] = s[q]; ls2[rg][c4*4+q] = s2[q]; }
    __syncthreads();
    if (tid < DIN) {
      float a = 0.f, bb = 0.f;
#pragma unroll
      for (int g = 0; g < 8; ++g) { a += ls[g][tid]; bb += ls2[g][tid]; }
      part_s[b * DIN + tid] = a;
      part_s2[b * DIN + tid] = bb;
    }
  } else if (b < 256) {
    int idx = (b - 64) * 256 + tid;        // [0, 49152)
    int k = idx / 384, c = idx % 384;
    Wc[idx] = (c < 256) ? Wt[(size_t)c * DIN + k] : Wo[(size_t)(c - 256) * DIN + k];
  } else if (b < 258) {
    int c = (b - 256) * 256 + tid;
    if (c < 384) bc[c] = (c < 256) ? bt[c] : bo[c - 256];
  } else {
    int g = (b - 258) * 256 + tid;         // [0, 4096) int4 = 64 KB
    ((int4*)deg)[g] = make_int4(0, 0, 0, 0);
  }
}

// ---------------- K2: GEMM blocks + A3-zero blocks -----------------------
// blocks [0,512): Hxh(bf16)/HW/sq for 16 rows each (BN finalize inlined);
// blocks [512, 512+8192): zero A3 row (b-512) with nontemporal stores.
__global__ __launch_bounds__(256) void k_rows(
    const float* __restrict__ H,
    const float* __restrict__ part_s, const float* __restrict__ part_s2,
    const float* __restrict__ gamma, const float* __restrict__ beta,
    const float* __restrict__ Wc, const float* __restrict__ bc,
    unsigned short* __restrict__ Hxh, float* __restrict__ HW,
    float* __restrict__ sq, float* __restrict__ A3) {
  int tid = threadIdx.x;
  int b = blockIdx.x;
  if (b >= 512) {
    vfloat4* row = (vfloat4*)(A3 + (size_t)(b - 512) * N);
    const vfloat4 z = {0.f, 0.f, 0.f, 0.f};
#pragma unroll
    for (int it = 0; it < 8; ++it)
      __builtin_nontemporal_store(z, row + tid + it * 256);
    return;
  }
  __shared__ __align__(16) float ssc[DIN];
  __shared__ __align__(16) float ssh[DIN];
  __shared__ float hn[16][DIN];   // 8 KB; reads below are wave-broadcast
  // inline BN finalize (identical bit-exact result in every block)
  if (tid < DIN) {
    float s = 0.f, s2 = 0.f;
    for (int g = 0; g < 64; ++g) { s += part_s[g*DIN+tid]; s2 += part_s2[g*DIN+tid]; }
    float mean = s * (1.0f / N);
    float var  = s2 * (1.0f / N) - mean * mean;
    float sc = rsqrtf(var + 1e-5f) * gamma[tid];
    ssc[tid] = sc;
    ssh[tid] = beta[tid] - mean * sc;
  }
  __syncthreads();
  int base = b * 16;
#pragma unroll
  for (int k = 0; k < 2; ++k) {
    int f = tid + k * 256;
    int r = f >> 5, c4 = f & 31;
    float4 h  = ((const float4*)(H + (size_t)(base + r) * DIN))[c4];
    float4 sc = ((const float4*)ssc)[c4];
    float4 sh = ((const float4*)ssh)[c4];
    h.x = h.x * sc.x + sh.x; h.y = h.y * sc.y + sh.y;
    h.z = h.z * sc.z + sh.z; h.w = h.w * sc.w + sh.w;
    ((float4*)hn[r])[c4] = h;
  }
  __syncthreads();
  int w = tid >> 6, lane = tid & 63;
  int r0 = w * 4;
  float acc[4][6];
#pragma unroll
  for (int r = 0; r < 4; ++r)
#pragma unroll
    for (int q = 0; q < 6; ++q) acc[r][q] = 0.f;

  for (int k4 = 0; k4 < 32; ++k4) {
    float4 h[4];
#pragma unroll
    for (int r = 0; r < 4; ++r) h[r] = ((const float4*)hn[r0 + r])[k4];
#pragma unroll
    for (int kk = 0; kk < 4; ++kk) {
      const float* wrow = Wc + (size_t)(k4 * 4 + kk) * 384 + lane;
      float wv[6];
#pragma unroll
      for (int q = 0; q < 6; ++q) wv[q] = wrow[64 * q];
#pragma unroll
      for (int r = 0; r < 4; ++r) {
        float hs = (kk == 0) ? h[r].x : (kk == 1) ? h[r].y
                 : (kk == 2) ? h[r].z : h[r].w;
#pragma unroll
        for (int q = 0; q < 6; ++q) acc[r][q] += hs * wv[q];
      }
    }
  }
#pragma unroll
  for (int r = 0; r < 4; ++r) {
    int row = base + r0 + r;
    float s = 0.f;
#pragma unroll
    for (int q = 0; q < 4; ++q) {
      float v = acc[r][q] + bc[lane + 64 * q];
      Hxh[(size_t)row * DTH + lane + 64 * q] = f2bf(v);
      s += v * v;
    }
#pragma unroll
    for (int off = 32; off > 0; off >>= 1) s += __shfl_xor(s, off, 64);
    if (lane == 0) sq[row] = s;
#pragma unroll
    for (int q = 4; q < 6; ++q) {
      float v = acc[r][q] + bc[lane + 64 * q];
      HW[(size_t)row * DOUT + lane + 64 * (q - 4)] = v;
    }
  }
}

// ---------------- K3: upper-tri edge pass, direct A3 scatter -------------
// A3 rows are fully zeroed by k_rows (previous kernel in stream) before any
// block here runs, so scattered writes of survivors are safe.
__global__ __launch_bounds__(256) void k_main(
    const float* __restrict__ A_adj, const unsigned short* __restrict__ Hxh,
    const float* __restrict__ sq, float* __restrict__ A3,
    float* __restrict__ deg, int* __restrict__ nnz_cnt,
    int* __restrict__ nnz_idx, float* __restrict__ nnz_val) {
  int i = blockIdx.x;
  int tid = threadIdx.x;
  __shared__ float4 hx4[64];          // hx_i as 64 float4
  __shared__ int   s_list[LISTCAP];
  __shared__ int   s_cnt;
  if (tid == 0) s_cnt = 0;
  ((float*)hx4)[tid] = __uint_as_float(((uint32_t)Hxh[(size_t)i * DTH + tid]) << 16);
  __syncthreads();

  const vfloat4* arow = (const vfloat4*)(A_adj + (size_t)i * N);
  int q0 = i >> 2;
  for (int q4 = q0 + tid; q4 < N / 4; q4 += 256) {
    vfloat4 a = __builtin_nontemporal_load(arow + q4);
    int jb = q4 * 4;
    float av[4] = {a.x, a.y, a.z, a.w};
#pragma unroll
    for (int q = 0; q < 4; ++q) {
      int j = jb + q;
      if (av[q] != 0.f && j >= i) {
        int p = atomicAdd(&s_cnt, 1);
        if (p < LISTCAP) s_list[p] = j;
      }
    }
  }
  __syncthreads();

  int M = min(s_cnt, LISTCAP);
  float sqi = sq[i];
  for (int t = tid; t < M; t += 256) {
    int j = s_list[t];
    bool keep = dropedge_keep((uint32_t)i * (uint32_t)N + (uint32_t)j);
    float dist;
    if (j == i) {
      dist = 1e-6f;                      // exact diagonal: sqrt(clip(0,1e-12))
    } else {
      const uint4* hj = (const uint4*)(Hxh + (size_t)j * DTH);
      float dot = 0.f;
#pragma unroll 8
      for (int c = 0; c < 32; ++c) {
        uint4 u = hj[c];
        float4 f0 = hx4[2 * c], f1 = hx4[2 * c + 1];
        dot += __uint_as_float(u.x << 16) * f0.x
             + __uint_as_float(u.x & 0xffff0000u) * f0.y
             + __uint_as_float(u.y << 16) * f0.z
             + __uint_as_float(u.y & 0xffff0000u) * f0.w
             + __uint_as_float(u.z << 16) * f1.x
             + __uint_as_float(u.z & 0xffff0000u) * f1.y
             + __uint_as_float(u.w << 16) * f1.z
             + __uint_as_float(u.w & 0xffff0000u) * f1.w;
      }
      dist = sqrtf(fmaxf(sqi + sq[j] - 2.0f * dot, 1e-12f));
    }
    float aval = expf(-0.2f * dist);
    float sg = fmaxf(1.0f / (1.0f + expf(-aval)), 0.1f);
    float bb = keep ? sg : 0.0f;
    float a2 = bb + ((i == j) ? 1.0f : 0.0f);
    float a3v = (a2 > 0.6f) ? a2 : 0.0f;
    if (a3v != 0.f) {
      A3[(size_t)i * N + j] = a3v;
      atomicAdd(&deg[i], a3v);
      int p = atomicAdd(&nnz_cnt[i], 1);
      if (p < ROWCAP) {
        nnz_idx[(size_t)i * ROWCAP + p] = j;
        nnz_val[(size_t)i * ROWCAP + p] = a3v;
      }
      if (j != i) {
        A3[(size_t)j * N + i] = a3v;
        atomicAdd(&deg[j], a3v);
        int p2 = atomicAdd(&nnz_cnt[j], 1);
        if (p2 < ROWCAP) {
          nnz_idx[(size_t)j * ROWCAP + p2] = i;
          nnz_val[(size_t)j * ROWCAP + p2] = a3v;
        }
      }
    }
  }
}

// ---------------- K4: out = lrelu(D^-1/2 A3 D^-1/2 @ HW) -----------------
__global__ __launch_bounds__(128) void k_post(
    const float* __restrict__ HW, const float* __restrict__ deg,
    const int* __restrict__ nnz_cnt, const int* __restrict__ nnz_idx,
    const float* __restrict__ nnz_val, float* __restrict__ out) {
  int i = blockIdx.x;
  int c = threadIdx.x;      // 128
  int cnt = min(nnz_cnt[i], ROWCAP);
  float acc = 0.f;
  for (int e = 0; e < cnt; ++e) {
    int j = nnz_idx[(size_t)i * ROWCAP + e];
    float v = nnz_val[(size_t)i * ROWCAP + e];
    acc += v * rsqrtf(deg[j]) * HW[(size_t)j * DOUT + c];
  }
  float o = rsqrtf(deg[i]) * acc;
  out[(size_t)i * DOUT + c] = (o >= 0.f) ? o : 0.01f * o;
}

// ---------------- launch --------------------------------------------------
extern "C" void kernel_launch(void* const* d_in, const int* in_sizes, int n_in,
                              void* d_out, int out_size, void* d_ws, size_t ws_size,
                              hipStream_t stream) {
  const float* H     = (const float*)d_in[0];
  const float* A_adj = (const float*)d_in[1];
  const float* gamma = (const float*)d_in[2];
  const float* beta  = (const float*)d_in[3];
  const float* Wt    = (const float*)d_in[4];
  const float* bt    = (const float*)d_in[5];
  const float* Wo    = (const float*)d_in[6];
  const float* bo    = (const float*)d_in[7];

  float* out = (float*)d_out;                    // [N, DOUT]
  float* A3  = out + (size_t)N * DOUT;           // [N, N]

  float* ws    = (float*)d_ws;
  unsigned short* Hxh = (unsigned short*)ws;      // N*256 bf16 (= N*128 floats)
  float* sq    = ws + (size_t)N * 128;            // N
  float* HW    = sq + N;                          // N*128
  float* deg   = HW + (size_t)N * DOUT;           // N   (deg+cnt contiguous!)
  int*   nnz_cnt = (int*)(deg + N);               // N
  int*   nnz_idx = nnz_cnt + N;                   // N*ROWCAP
  float* nnz_val = (float*)(nnz_idx + (size_t)N * ROWCAP); // N*ROWCAP
  float* part_s  = nnz_val + (size_t)N * ROWCAP;  // 64*128
  float* part_s2 = part_s + 64 * DIN;             // 64*128
  float* Wc      = part_s2 + 64 * DIN;            // 128*384
  float* bc      = Wc + 128 * 384;                // 384

  k_pre<<<274, 256, 0, stream>>>(H, Wt, bt, Wo, bo, part_s, part_s2, Wc, bc, deg);
  k_rows<<<512 + N, 256, 0, stream>>>(H, part_s, part_s2, gamma, beta, Wc, bc,
                                      Hxh, HW, sq, A3);
  k_main<<<N, 256, 0, stream>>>(A_adj, Hxh, sq, A3, deg, nnz_cnt, nnz_idx, nnz_val);
  k_post<<<N, DOUT, 0, stream>>>(HW, deg, nnz_cnt, nnz_idx, nnz_val, out);
}